// Round 12
// baseline (653.976 us; speedup 1.0000x reference)
//
#include <hip/hip_runtime.h>
#include <hip/hip_bf16.h>

#define NN 50000
#define EE 800000
#define GG 64
#define LL 3
#define CC 4
#define HH 64
#define BN_EPS 1e-5f
#define NSHADOW 4
#define SBLK 196          // ceil(NN/256) node-parallel blocks
#define GIN_BLOCKS 2048   // grid-stride GIN kernels
#define NODE_RANGE 6250   // NN / 8 (XCD binning for k_fill)

// NOTE: harness passes ALL integer inputs as int32 (edge_index/batch included).
// NOTE: cooperative launch + grid.sync measured 4x SLOWER than kernel-boundary
//       barriers (R5) — do not reintroduce.
// NOTE: single-block k_final measured 90us (latency-bound) — keep final MLP split (R7).
// NOTE: 4-nodes/wave float4 GIN layout at 800 blocks measured +280us (R7: TLP
//       starvation) — keep scalar layout + big grid; R12 pairs 2 nodes/wave only
//       to amortize W loads (64 fewer VMEM/pair), gathers unchanged.
// NOTE: R11: uniform-index readlane broadcasts: 745->646us (GIN is VALU-issue bound).
// NOTE: R12: k_fill WRITE_SIZE 51MB for 3.2MB adj (cross-XCD 4B scatter) ->
//       8-pass dst-range binning with range = blockIdx&7 (XCD heuristic).

__device__ __forceinline__ float bcast(float v, int j) {
    return __int_as_float(__builtin_amdgcn_readlane(__float_as_int(v), j));
}

// ---------------- setup kernels ----------------

// fused: x fp32->bf16 convert + degree count + cluster histogram
__global__ void k_deghist(const int* __restrict__ dst, int* __restrict__ deg,
                          const int* __restrict__ labels, int* __restrict__ blockcnt,
                          const float* __restrict__ x_in, __hip_bfloat16* __restrict__ xw) {
    __shared__ int cnt[CC];
    int tid = threadIdx.x;
    for (int i = blockIdx.x * 256 + tid; i < NN * 64; i += gridDim.x * 256)
        xw[i] = __float2bfloat16(x_in[i]);
    bool hist = (blockIdx.x < SBLK);
    if (hist && tid < CC) cnt[tid] = 0;
    __syncthreads();
    int gid = blockIdx.x * 256 + tid;
    if (gid < EE) atomicAdd(&deg[dst[gid]], 1);
    if (hist && gid < NN) atomicAdd(&cnt[labels[gid]], 1);
    __syncthreads();
    if (hist && tid < CC) blockcnt[tid * SBLK + blockIdx.x] = cnt[tid];
}

__global__ __launch_bounds__(256) void k_scancombo(
    const int* __restrict__ deg, int* __restrict__ rowptr, int* __restrict__ dpart,
    const int* __restrict__ blockcnt, int* __restrict__ coffs, int* __restrict__ ccount) {
    __shared__ int smem[CC * 256];
    int tid = threadIdx.x;
    if (blockIdx.x < SBLK) {
        int i = blockIdx.x * 256 + tid;
        int v = (i < NN) ? deg[i] : 0;
        smem[tid] = v;
        __syncthreads();
        for (int off = 1; off < 256; off <<= 1) {
            int u = (tid >= off) ? smem[tid - off] : 0;
            __syncthreads();
            smem[tid] += u;
            __syncthreads();
        }
        if (i < NN) rowptr[i] = smem[tid] - v;  // local exclusive
        if (tid == 255) dpart[blockIdx.x] = smem[255];
    } else {
        int own[CC];
        for (int c = 0; c < CC; c++) {
            own[c] = (tid < SBLK) ? blockcnt[c * SBLK + tid] : 0;
            smem[c * 256 + tid] = own[c];
        }
        __syncthreads();
        for (int off = 1; off < 256; off <<= 1) {
            int v[CC];
            for (int c = 0; c < CC; c++) v[c] = (tid >= off) ? smem[c * 256 + tid - off] : 0;
            __syncthreads();
            for (int c = 0; c < CC; c++) smem[c * 256 + tid] += v[c];
            __syncthreads();
        }
        if (tid < SBLK)
            for (int c = 0; c < CC; c++) coffs[c * SBLK + tid] = smem[c * 256 + tid] - own[c];
        if (tid == 0)
            for (int c = 0; c < CC; c++) ccount[c] = smem[c * 256 + 255];
    }
}

__global__ __launch_bounds__(256) void k_dscan2(int* __restrict__ dpart,
                                                int* __restrict__ dbase,
                                                int* __restrict__ rowptr) {
    __shared__ int s[256];
    int tid = threadIdx.x;
    int v = (tid < SBLK) ? dpart[tid] : 0;
    s[tid] = v;
    __syncthreads();
    for (int off = 1; off < 256; off <<= 1) {
        int u = (tid >= off) ? s[tid - off] : 0;
        __syncthreads();
        s[tid] += u;
        __syncthreads();
    }
    if (tid < SBLK) dbase[tid] = s[tid] - v;
    if (tid == 0) rowptr[NN] = EE;
}

__global__ __launch_bounds__(256) void k_cfill_dscan3(
    int* __restrict__ rowptr, const int* __restrict__ dbase, int* __restrict__ cursor,
    const int* __restrict__ labels, const int* __restrict__ coffs, int* __restrict__ clist) {
    __shared__ int pos[CC];
    int tid = threadIdx.x;
    if (tid < CC) pos[tid] = coffs[tid * SBLK + blockIdx.x];
    __syncthreads();
    int i = blockIdx.x * 256 + tid;
    if (i < NN) {
        int r = rowptr[i] + dbase[blockIdx.x];
        rowptr[i] = r;
        cursor[i] = r;
        int c = labels[i];
        int p = atomicAdd(&pos[c], 1);
        clist[c * NN + p] = i;
    }
}

// XCD-binned CSR fill: 8 dst-range passes; range = blockIdx&7 so writes to a
// given contiguous adj region come (heuristically) from one XCD's L2.
// adj stores BYTE offsets of bf16 rows: src*128 = src<<7
__global__ void k_fill(const int* __restrict__ src, const int* __restrict__ dst,
                       int* __restrict__ cursor, int* __restrict__ adj) {
    int range = blockIdx.x & 7;
    int chunk = blockIdx.x >> 3;
    int e = chunk * 256 + threadIdx.x;
    if (e < EE) {
        int d = dst[e];
        int lo = range * NODE_RANGE;
        if (d >= lo && d < lo + NODE_RANGE) {
            int pos = atomicAdd(&cursor[d], 1);
            adj[pos] = src[e] << 7;
        }
    }
}

// ---------------- per-(t,c) kernels (scalar layout, 2-node pairs) ----------------
// Kernel A: per wave, nodes (2w, 2w+1): gather each (8 indep chains), then one
// joint MLP loop amortizing W1 loads across the pair. BN partials; optional
// fused pool of previous layer.
__global__ __launch_bounds__(256) void k_gin_a(
    const __hip_bfloat16* __restrict__ xw, const int* __restrict__ adj,
    const int* __restrict__ rowptr, const int* __restrict__ clist_c,
    const int* __restrict__ ccount_c, const float* __restrict__ W1,
    const float* __restrict__ b1, __hip_bfloat16* __restrict__ h1buf,
    float* __restrict__ bnacc,
    const int* __restrict__ batch, float* __restrict__ z, int tpool) {
    __shared__ float lds_red[4][128];
    int cnt = *ccount_c;
    int lane = threadIdx.x & 63;
    int wave = threadIdx.x >> 6;
    int wid = blockIdx.x * 4 + wave;
    int nwaves = gridDim.x * 4;
    const char* xwb = (const char*)xw;
    float sS = 0.f, sQ = 0.f;

    for (int p = wid * 2; p < cnt; p += nwaves * 2) {
        int i1 = p + 1;
        bool has1 = (i1 < cnt);
        float acc[2];
        #pragma unroll
        for (int nn = 0; nn < 2; nn++) {
            if (nn == 1 && !has1) { acc[1] = 0.f; break; }
            int node = clist_c[p + nn];
            int rb = rowptr[node], re = rowptr[node + 1];
            float a0 = __bfloat162float(xw[(size_t)node * 64 + lane]);
            float a1 = 0.f, a2 = 0.f, a3 = 0.f, a4 = 0.f, a5 = 0.f, a6 = 0.f, a7 = 0.f;
            int base = rb, rem = re - rb;
            while (rem > 0) {
                int take = min(rem, 64);
                int nb = adj[base + min(lane, take - 1)];  // byte offsets
                int j = 0;
                for (; j + 8 <= take; j += 8) {
                    int o0 = __builtin_amdgcn_readlane(nb, j + 0);
                    int o1 = __builtin_amdgcn_readlane(nb, j + 1);
                    int o2 = __builtin_amdgcn_readlane(nb, j + 2);
                    int o3 = __builtin_amdgcn_readlane(nb, j + 3);
                    int o4 = __builtin_amdgcn_readlane(nb, j + 4);
                    int o5 = __builtin_amdgcn_readlane(nb, j + 5);
                    int o6 = __builtin_amdgcn_readlane(nb, j + 6);
                    int o7 = __builtin_amdgcn_readlane(nb, j + 7);
                    a0 += __bfloat162float(((const __hip_bfloat16*)(xwb + o0))[lane]);
                    a1 += __bfloat162float(((const __hip_bfloat16*)(xwb + o1))[lane]);
                    a2 += __bfloat162float(((const __hip_bfloat16*)(xwb + o2))[lane]);
                    a3 += __bfloat162float(((const __hip_bfloat16*)(xwb + o3))[lane]);
                    a4 += __bfloat162float(((const __hip_bfloat16*)(xwb + o4))[lane]);
                    a5 += __bfloat162float(((const __hip_bfloat16*)(xwb + o5))[lane]);
                    a6 += __bfloat162float(((const __hip_bfloat16*)(xwb + o6))[lane]);
                    a7 += __bfloat162float(((const __hip_bfloat16*)(xwb + o7))[lane]);
                }
                for (; j < take; j++) {
                    int o = __builtin_amdgcn_readlane(nb, j);
                    a0 += __bfloat162float(((const __hip_bfloat16*)(xwb + o))[lane]);
                }
                base += take; rem -= take;
            }
            acc[nn] = ((a0 + a1) + (a2 + a3)) + ((a4 + a5) + (a6 + a7));
        }
        // joint MLP: one W1 load per j serves both nodes
        float bb = b1[lane];
        float s0 = bb, s1 = bb;
        #pragma unroll
        for (int j = 0; j < 64; j++) {
            float w = W1[j * 64 + lane];
            s0 += bcast(acc[0], j) * w;
            s1 += bcast(acc[1], j) * w;
        }
        __hip_bfloat16 hb0 = __float2bfloat16(s0);
        h1buf[(size_t)p * 64 + lane] = hb0;
        float st0 = __bfloat162float(hb0);
        sS += st0; sQ += st0 * st0;
        if (has1) {
            __hip_bfloat16 hb1 = __float2bfloat16(s1);
            h1buf[(size_t)i1 * 64 + lane] = hb1;
            float st1 = __bfloat162float(hb1);
            sS += st1; sQ += st1 * st1;
        }
    }
    lds_red[wave][lane] = sS;
    lds_red[wave][64 + lane] = sQ;
    __syncthreads();
    if (threadIdx.x < 128) {
        float v = lds_red[0][threadIdx.x] + lds_red[1][threadIdx.x] +
                  lds_red[2][threadIdx.x] + lds_red[3][threadIdx.x];
        atomicAdd(&bnacc[(blockIdx.x & (NSHADOW - 1)) * 128 + threadIdx.x], v);
    }
    // -------- fused pool of previous layer (reads same xw state) --------
    if (tpool >= 0) {
        int lo = wid * 64;
        if (lo < NN) {
            int hi = min(lo + 64, NN);
            float acc = 0.f;
            int curg = batch[lo];
            for (int n = lo; n < hi; n++) {
                int g = batch[n];
                if (g != curg) {
                    atomicAdd(&z[curg * (HH * LL) + tpool * HH + lane], acc);
                    acc = 0.f;
                    curg = g;
                }
                acc += __bfloat162float(xw[(size_t)n * 64 + lane]);
            }
            atomicAdd(&z[curg * (HH * LL) + tpool * HH + lane], acc);
        }
    }
}

// Kernel C: BN + ReLU + Lin2 with 2-node W2 amortization; x[node] = h2 (bf16).
__global__ __launch_bounds__(256) void k_gin_c(
    __hip_bfloat16* __restrict__ xw, const int* __restrict__ clist_c,
    const int* __restrict__ ccount_c, const float* __restrict__ g1,
    const float* __restrict__ be1, const float* __restrict__ W2,
    const float* __restrict__ b2, const __hip_bfloat16* __restrict__ h1buf,
    const float* __restrict__ bnacc) {
    __shared__ float lds_scale[64];
    __shared__ float lds_shift[64];
    int cnt = *ccount_c;
    int lane = threadIdx.x & 63;
    int wave = threadIdx.x >> 6;
    int wid = blockIdx.x * 4 + wave;
    int nwaves = gridDim.x * 4;
    if (threadIdx.x < 64) {
        float s = 0.f, q = 0.f;
        #pragma unroll
        for (int sh = 0; sh < NSHADOW; sh++) {
            s += bnacc[sh * 128 + threadIdx.x];
            q += bnacc[sh * 128 + 64 + threadIdx.x];
        }
        float fc = fmaxf((float)cnt, 1.f);
        float mean = s / fc;
        float var = q / fc - mean * mean;
        float sc = g1[threadIdx.x] * rsqrtf(var + BN_EPS);
        lds_scale[threadIdx.x] = sc;
        lds_shift[threadIdx.x] = be1[threadIdx.x] - mean * sc;
    }
    __syncthreads();
    float scl = lds_scale[lane];
    float sft = lds_shift[lane];
    for (int p = wid * 2; p < cnt; p += nwaves * 2) {
        int i1 = p + 1;
        bool has1 = (i1 < cnt);
        float h0 = __bfloat162float(h1buf[(size_t)p * 64 + lane]);
        float h1v = has1 ? __bfloat162float(h1buf[(size_t)i1 * 64 + lane]) : 0.f;
        float a0 = fmaxf(h0 * scl + sft, 0.f);
        float a1 = fmaxf(h1v * scl + sft, 0.f);
        float bb = b2[lane];
        float s0 = bb, s1 = bb;
        #pragma unroll
        for (int j = 0; j < 64; j++) {
            float w = W2[j * 64 + lane];
            s0 += bcast(a0, j) * w;
            s1 += bcast(a1, j) * w;
        }
        xw[(size_t)clist_c[p] * 64 + lane] = __float2bfloat16(s0);
        if (has1) xw[(size_t)clist_c[i1] * 64 + lane] = __float2bfloat16(s1);
    }
}

// ---------------- pooling (standalone, used for last layer) ----------------
__global__ void k_pool(const __hip_bfloat16* __restrict__ xw, const int* __restrict__ batch,
                       float* __restrict__ z, int t) {
    const int CHUNK = 64;
    int lane = threadIdx.x & 63;
    int wg = (blockIdx.x * blockDim.x + threadIdx.x) >> 6;
    int lo = wg * CHUNK;
    if (lo >= NN) return;
    int hi = min(lo + CHUNK, NN);
    float acc = 0.f;
    int curg = batch[lo];
    for (int n = lo; n < hi; n++) {
        int g = batch[n];
        if (g != curg) {
            atomicAdd(&z[curg * (HH * LL) + t * HH + lane], acc);
            acc = 0.f;
            curg = g;
        }
        acc += __bfloat162float(xw[(size_t)n * 64 + lane]);
    }
    atomicAdd(&z[curg * (HH * LL) + t * HH + lane], acc);
}

// ---------------- final MLP (split for parallelism, R7-proven) ----------------
__global__ __launch_bounds__(256) void k_final1(
    const float* __restrict__ z, const float* __restrict__ Wp1,
    const float* __restrict__ bp1, float* __restrict__ hbuf) {
    __shared__ float red[256];
    int g = blockIdx.x;
    int k = threadIdx.x & 63;
    int part = threadIdx.x >> 6;  // 4 parts x 48 j's
    float s = 0.f;
    #pragma unroll 8
    for (int j = part * 48; j < (part + 1) * 48; j++)
        s += z[g * (HH * LL) + j] * Wp1[j * 64 + k];
    red[threadIdx.x] = s;
    __syncthreads();
    if (part == 0)
        hbuf[g * 64 + k] = red[k] + red[64 + k] + red[128 + k] + red[192 + k] + bp1[k];
}

__global__ __launch_bounds__(256) void k_final2(
    const float* __restrict__ hbuf, const float* __restrict__ gp,
    const float* __restrict__ bep, const float* __restrict__ Wp2,
    const float* __restrict__ bp2, float* __restrict__ out) {
    __shared__ float lds[64 * 64];
    __shared__ float sscale[64];
    __shared__ float sshift[64];
    int tid = threadIdx.x;
    for (int i = tid; i < 64 * 64; i += 256) lds[i] = hbuf[i];
    __syncthreads();
    if (tid < 64) {
        float s = 0.f, q = 0.f;
        for (int g = 0; g < 64; g++) { float v = lds[g * 64 + tid]; s += v; q += v * v; }
        float mean = s / 64.f;
        float var = q / 64.f - mean * mean;
        float sc = gp[tid] * rsqrtf(var + BN_EPS);
        sscale[tid] = sc;
        sshift[tid] = bep[tid] - mean * sc;
    }
    __syncthreads();
    for (int i = tid; i < 64 * 64; i += 256) {
        int k = i & 63;
        lds[i] = fmaxf(lds[i] * sscale[k] + sshift[k], 0.f);
    }
    __syncthreads();
    for (int i = tid; i < 64 * 64; i += 256) {
        int g = i >> 6, o = i & 63;
        float s = bp2[o];
        #pragma unroll 8
        for (int k = 0; k < 64; k++) s += lds[g * 64 + k] * Wp2[k * 64 + o];
        out[g * 64 + o] = s;
    }
}

// ---------------- launch ----------------
extern "C" void kernel_launch(void* const* d_in, const int* in_sizes, int n_in,
                              void* d_out, int out_size, void* d_ws, size_t ws_size,
                              hipStream_t stream) {
    const float* x_in = (const float*)d_in[0];
    const int* labels = (const int*)d_in[1];
    const int* esrc = (const int*)d_in[2];
    const int* edst = esrc + EE;
    const int* batch = (const int*)d_in[3];
    const float* W1 = (const float*)d_in[4];
    const float* b1 = (const float*)d_in[5];
    const float* g1 = (const float*)d_in[6];
    const float* be1 = (const float*)d_in[7];
    const float* W2 = (const float*)d_in[8];
    const float* b2 = (const float*)d_in[9];
    const float* Wp1 = (const float*)d_in[10];
    const float* bp1 = (const float*)d_in[11];
    const float* gp = (const float*)d_in[12];
    const float* bep = (const float*)d_in[13];
    const float* Wp2 = (const float*)d_in[14];
    const float* bp2 = (const float*)d_in[15];
    float* out = (float*)d_out;

    char* p = (char*)d_ws;
    auto carve = [&](size_t bytes) -> void* {
        void* r = (void*)p;
        p += (bytes + 255) & ~(size_t)255;
        return r;
    };
    // ---- zeroed region (one memset) ----
    float* bnacc = (float*)carve((size_t)LL * CC * NSHADOW * 128 * 4);
    float* z     = (float*)carve((size_t)GG * HH * LL * 4);
    int*   deg   = (int*)carve((size_t)NN * 4);
    size_t zero_bytes = (size_t)(p - (char*)d_ws);
    // ---- rest ----
    int*   ccount  = (int*)carve(CC * 4);
    int*   blockcnt= (int*)carve((size_t)CC * SBLK * 4);
    int*   coffs   = (int*)carve((size_t)CC * SBLK * 4);
    int*   dpart   = (int*)carve((size_t)SBLK * 4);
    int*   dbase   = (int*)carve((size_t)SBLK * 4);
    __hip_bfloat16* xw    = (__hip_bfloat16*)carve((size_t)NN * 64 * 2);
    __hip_bfloat16* h1buf = (__hip_bfloat16*)carve((size_t)NN * 64 * 2);
    float* hbuf    = (float*)carve((size_t)GG * 64 * 4);
    int*   rowptr  = (int*)carve((size_t)(NN + 1) * 4);
    int*   cursor  = (int*)carve((size_t)NN * 4);
    int*   adj     = (int*)carve((size_t)EE * 4);
    int*   clist   = (int*)carve((size_t)CC * NN * 4);

    hipMemsetAsync(d_ws, 0, zero_bytes, stream);

    k_deghist<<<(EE + 255) / 256, 256, 0, stream>>>(edst, deg, labels, blockcnt, x_in, xw);
    k_scancombo<<<SBLK + 1, 256, 0, stream>>>(deg, rowptr, dpart, blockcnt, coffs, ccount);
    k_dscan2<<<1, 256, 0, stream>>>(dpart, dbase, rowptr);
    k_cfill_dscan3<<<SBLK, 256, 0, stream>>>(rowptr, dbase, cursor, labels, coffs, clist);
    k_fill<<<((EE + 255) / 256) * 8, 256, 0, stream>>>(esrc, edst, cursor, adj);

    for (int t = 0; t < LL; t++) {
        for (int c = 0; c < CC; c++) {
            int tc = t * CC + c;
            int tpool = (c == 0) ? (t - 1) : -1;  // fuse previous layer's pool into A(t,0)
            k_gin_a<<<GIN_BLOCKS, 256, 0, stream>>>(
                xw, adj, rowptr, clist + c * NN, ccount + c,
                W1 + (size_t)tc * 4096, b1 + (size_t)tc * 64, h1buf,
                bnacc + (size_t)tc * NSHADOW * 128, batch, z, tpool);
            k_gin_c<<<GIN_BLOCKS, 256, 0, stream>>>(
                xw, clist + c * NN, ccount + c,
                g1 + (size_t)tc * 64, be1 + (size_t)tc * 64,
                W2 + (size_t)tc * 4096, b2 + (size_t)tc * 64, h1buf,
                bnacc + (size_t)tc * NSHADOW * 128);
        }
    }
    // last layer's pool (standalone)
    {
        int pool_waves = (NN + 63) / 64;
        int pool_blocks = (pool_waves * 64 + 255) / 256;
        k_pool<<<pool_blocks, 256, 0, stream>>>(xw, batch, z, LL - 1);
    }
    k_final1<<<GG, 256, 0, stream>>>(z, Wp1, bp1, hbuf);
    k_final2<<<1, 256, 0, stream>>>(hbuf, gp, bep, Wp2, bp2, out);
}

// Round 13
// 563.416 us; speedup vs baseline: 1.1607x; 1.1607x over previous
//
#include <hip/hip_runtime.h>
#include <hip/hip_bf16.h>

#define NN 50000
#define EE 800000
#define GG 64
#define LL 3
#define CC 4
#define HH 64
#define BN_EPS 1e-5f
#define NSHADOW 4
#define SBLK 196          // ceil(NN/256) node-parallel blocks
#define GIN_BLOCKS 2048   // grid-stride gather kernels (8192 waves)
#define MM_BLOCKS 256     // MFMA GEMM kernels (1024 waves >= 782 tiles)

// NOTE: harness passes ALL integer inputs as int32 (edge_index/batch included).
// NOTE: cooperative launch + grid.sync 4x SLOWER than kernel barriers (R5).
// NOTE: single-block k_final 90us latency-bound -> final MLP split (R7).
// NOTE: multi-node-per-wave gather serializes latency chains (R7: -280us at 4/wave,
//       R12: neutral-negative at 2/wave) — gather stays 1 node/wave, big grid.
// NOTE: R11: GIN kernels are VALU-ISSUE bound; readlane broadcasts 745->646us.
// NOTE: R13: MLPs moved to MFMA (16x16x32 bf16): gather-only kernel + GEMM kernels.
//       Fragment layouts: A[m=lane&15][k=quad*8+j]; C/D[col=lane&15][row=quad*4+reg].

typedef __attribute__((ext_vector_type(8))) short bf16x8;
typedef __attribute__((ext_vector_type(4))) float f32x4;

__device__ __forceinline__ float bf2f(short s) {
    return __int_as_float(((int)(unsigned short)s) << 16);
}
__device__ __forceinline__ short f2bf(float v) {
    __hip_bfloat16 hb = __float2bfloat16(v);
    return *(short*)&hb;
}

// ---------------- setup kernels ----------------

// fused: x fp32->bf16 convert + degree count + cluster histogram
__global__ void k_deghist(const int* __restrict__ dst, int* __restrict__ deg,
                          const int* __restrict__ labels, int* __restrict__ blockcnt,
                          const float* __restrict__ x_in, __hip_bfloat16* __restrict__ xw) {
    __shared__ int cnt[CC];
    int tid = threadIdx.x;
    for (int i = blockIdx.x * 256 + tid; i < NN * 64; i += gridDim.x * 256)
        xw[i] = __float2bfloat16(x_in[i]);
    bool hist = (blockIdx.x < SBLK);
    if (hist && tid < CC) cnt[tid] = 0;
    __syncthreads();
    int gid = blockIdx.x * 256 + tid;
    if (gid < EE) atomicAdd(&deg[dst[gid]], 1);
    if (hist && gid < NN) atomicAdd(&cnt[labels[gid]], 1);
    __syncthreads();
    if (hist && tid < CC) blockcnt[tid * SBLK + blockIdx.x] = cnt[tid];
}

// pack W1/W2 (fp32 row-major [k][n]) into bf16 MFMA B-fragment order:
// wf[m][f = colt*2+fragk][lane][j] = W_m[fragk*32 + (lane>>4)*8 + j][colt*16 + (lane&15)]
__global__ void k_wpack(const float* __restrict__ W1, const float* __restrict__ W2,
                        short* __restrict__ wf) {
    int o = blockIdx.x * 256 + threadIdx.x;  // 24*4096 total
    if (o >= 24 * 4096) return;
    int m = o >> 12;
    int r = o & 4095;
    int colt = r >> 10;
    int fragk = (r >> 9) & 1;
    int lane = (r >> 3) & 63;
    int j = r & 7;
    int k = fragk * 32 + ((lane >> 4) << 3) + j;
    int n = colt * 16 + (lane & 15);
    const float* src = (m < 12) ? (W1 + (size_t)m * 4096) : (W2 + (size_t)(m - 12) * 4096);
    wf[o] = f2bf(src[k * 64 + n]);
}

__global__ __launch_bounds__(256) void k_scancombo(
    const int* __restrict__ deg, int* __restrict__ rowptr, int* __restrict__ dpart,
    const int* __restrict__ blockcnt, int* __restrict__ coffs, int* __restrict__ ccount) {
    __shared__ int smem[CC * 256];
    int tid = threadIdx.x;
    if (blockIdx.x < SBLK) {
        int i = blockIdx.x * 256 + tid;
        int v = (i < NN) ? deg[i] : 0;
        smem[tid] = v;
        __syncthreads();
        for (int off = 1; off < 256; off <<= 1) {
            int u = (tid >= off) ? smem[tid - off] : 0;
            __syncthreads();
            smem[tid] += u;
            __syncthreads();
        }
        if (i < NN) rowptr[i] = smem[tid] - v;  // local exclusive
        if (tid == 255) dpart[blockIdx.x] = smem[255];
    } else {
        int own[CC];
        for (int c = 0; c < CC; c++) {
            own[c] = (tid < SBLK) ? blockcnt[c * SBLK + tid] : 0;
            smem[c * 256 + tid] = own[c];
        }
        __syncthreads();
        for (int off = 1; off < 256; off <<= 1) {
            int v[CC];
            for (int c = 0; c < CC; c++) v[c] = (tid >= off) ? smem[c * 256 + tid - off] : 0;
            __syncthreads();
            for (int c = 0; c < CC; c++) smem[c * 256 + tid] += v[c];
            __syncthreads();
        }
        if (tid < SBLK)
            for (int c = 0; c < CC; c++) coffs[c * SBLK + tid] = smem[c * 256 + tid] - own[c];
        if (tid == 0)
            for (int c = 0; c < CC; c++) ccount[c] = smem[c * 256 + 255];
    }
}

__global__ __launch_bounds__(256) void k_dscan2(int* __restrict__ dpart,
                                                int* __restrict__ dbase,
                                                int* __restrict__ rowptr) {
    __shared__ int s[256];
    int tid = threadIdx.x;
    int v = (tid < SBLK) ? dpart[tid] : 0;
    s[tid] = v;
    __syncthreads();
    for (int off = 1; off < 256; off <<= 1) {
        int u = (tid >= off) ? s[tid - off] : 0;
        __syncthreads();
        s[tid] += u;
        __syncthreads();
    }
    if (tid < SBLK) dbase[tid] = s[tid] - v;
    if (tid == 0) rowptr[NN] = EE;
}

__global__ __launch_bounds__(256) void k_cfill_dscan3(
    int* __restrict__ rowptr, const int* __restrict__ dbase, int* __restrict__ cursor,
    const int* __restrict__ labels, const int* __restrict__ coffs, int* __restrict__ clist) {
    __shared__ int pos[CC];
    int tid = threadIdx.x;
    if (tid < CC) pos[tid] = coffs[tid * SBLK + blockIdx.x];
    __syncthreads();
    int i = blockIdx.x * 256 + tid;
    if (i < NN) {
        int r = rowptr[i] + dbase[blockIdx.x];
        rowptr[i] = r;
        cursor[i] = r;
        int c = labels[i];
        int p = atomicAdd(&pos[c], 1);
        clist[c * NN + p] = i;
    }
}

// adj stores BYTE offsets of bf16 rows: src*128 = src<<7  (R11-proven simple fill)
__global__ void k_fill(const int* __restrict__ src, const int* __restrict__ dst,
                       int* __restrict__ cursor, int* __restrict__ adj) {
    int e = blockIdx.x * blockDim.x + threadIdx.x;
    if (e < EE) {
        int d = dst[e];
        int pos = atomicAdd(&cursor[d], 1);
        adj[pos] = src[e] << 7;
    }
}

// ---------------- gather kernel (R11-proven loop, MLP removed) ----------------
// agg[idx] = x[node] + sum_{j->node} x[j]  (bf16 out), 1 node/wave, 8 indep chains.
// Optional fused pool of previous layer (tpool >= 0).
__global__ __launch_bounds__(256) void k_gather(
    const __hip_bfloat16* __restrict__ xw, const int* __restrict__ adj,
    const int* __restrict__ rowptr, const int* __restrict__ clist_c,
    const int* __restrict__ ccount_c, __hip_bfloat16* __restrict__ aggbuf,
    const int* __restrict__ batch, float* __restrict__ z, int tpool) {
    int cnt = *ccount_c;
    int lane = threadIdx.x & 63;
    int wave = threadIdx.x >> 6;
    int wid = blockIdx.x * 4 + wave;
    int nwaves = gridDim.x * 4;
    const char* xwb = (const char*)xw;
    int idx = wid;
    int node_next = (idx < cnt) ? clist_c[idx] : 0;
    for (; idx < cnt; idx += nwaves) {
        int node = node_next;
        int nidx = idx + nwaves;
        if (nidx < cnt) node_next = clist_c[nidx];  // prefetch next node id
        int rb = rowptr[node], re = rowptr[node + 1];
        float a0 = __bfloat162float(xw[(size_t)node * 64 + lane]);
        float a1 = 0.f, a2 = 0.f, a3 = 0.f, a4 = 0.f, a5 = 0.f, a6 = 0.f, a7 = 0.f;
        int base = rb, rem = re - rb;
        while (rem > 0) {
            int take = min(rem, 64);
            int nb = adj[base + min(lane, take - 1)];  // byte offsets
            int j = 0;
            for (; j + 8 <= take; j += 8) {
                int o0 = __builtin_amdgcn_readlane(nb, j + 0);
                int o1 = __builtin_amdgcn_readlane(nb, j + 1);
                int o2 = __builtin_amdgcn_readlane(nb, j + 2);
                int o3 = __builtin_amdgcn_readlane(nb, j + 3);
                int o4 = __builtin_amdgcn_readlane(nb, j + 4);
                int o5 = __builtin_amdgcn_readlane(nb, j + 5);
                int o6 = __builtin_amdgcn_readlane(nb, j + 6);
                int o7 = __builtin_amdgcn_readlane(nb, j + 7);
                a0 += __bfloat162float(((const __hip_bfloat16*)(xwb + o0))[lane]);
                a1 += __bfloat162float(((const __hip_bfloat16*)(xwb + o1))[lane]);
                a2 += __bfloat162float(((const __hip_bfloat16*)(xwb + o2))[lane]);
                a3 += __bfloat162float(((const __hip_bfloat16*)(xwb + o3))[lane]);
                a4 += __bfloat162float(((const __hip_bfloat16*)(xwb + o4))[lane]);
                a5 += __bfloat162float(((const __hip_bfloat16*)(xwb + o5))[lane]);
                a6 += __bfloat162float(((const __hip_bfloat16*)(xwb + o6))[lane]);
                a7 += __bfloat162float(((const __hip_bfloat16*)(xwb + o7))[lane]);
            }
            for (; j < take; j++) {
                int o = __builtin_amdgcn_readlane(nb, j);
                a0 += __bfloat162float(((const __hip_bfloat16*)(xwb + o))[lane]);
            }
            base += take; rem -= take;
        }
        float acc = ((a0 + a1) + (a2 + a3)) + ((a4 + a5) + (a6 + a7));
        aggbuf[(size_t)idx * 64 + lane] = __float2bfloat16(acc);
    }
    // -------- fused pool of previous layer (reads same xw state) --------
    if (tpool >= 0) {
        int lo = wid * 64;
        if (lo < NN) {
            int hi = min(lo + 64, NN);
            float acc = 0.f;
            int curg = batch[lo];
            for (int n = lo; n < hi; n++) {
                int g = batch[n];
                if (g != curg) {
                    atomicAdd(&z[curg * (HH * LL) + tpool * HH + lane], acc);
                    acc = 0.f;
                    curg = g;
                }
                acc += __bfloat162float(xw[(size_t)n * 64 + lane]);
            }
            atomicAdd(&z[curg * (HH * LL) + tpool * HH + lane], acc);
        }
    }
}

// ---------------- MFMA Lin1: h1 = agg @ W1 + b1 ; BN partials ----------------
__global__ __launch_bounds__(256) void k_lin1(
    const __hip_bfloat16* __restrict__ aggbuf, const int* __restrict__ ccount_c,
    const short* __restrict__ wf1, const float* __restrict__ b1c,
    __hip_bfloat16* __restrict__ h1buf, float* __restrict__ bnacc) {
    int cnt = *ccount_c;
    int tiles = (cnt + 15) >> 4;
    int lane = threadIdx.x & 63;
    int wave = threadIdx.x >> 6;
    int wid = blockIdx.x * 4 + wave;
    int nwaves = gridDim.x * 4;
    int quad = lane >> 4;
    int l15 = lane & 15;

    bf16x8 wb[8];
    #pragma unroll
    for (int f = 0; f < 8; f++)
        wb[f] = *(const bf16x8*)(wf1 + f * 512 + lane * 8);
    float bcol[4];
    #pragma unroll
    for (int colt = 0; colt < 4; colt++) bcol[colt] = b1c[colt * 16 + l15];

    float sS[4] = {0.f, 0.f, 0.f, 0.f};
    float sQ[4] = {0.f, 0.f, 0.f, 0.f};

    for (int tile = wid; tile < tiles; tile += nwaves) {
        int tb = tile << 4;
        int row = tb + l15;
        const __hip_bfloat16* ar = aggbuf + (size_t)row * 64 + quad * 8;
        bf16x8 a0 = *(const bf16x8*)ar;
        bf16x8 a1 = *(const bf16x8*)(ar + 32);
        #pragma unroll
        for (int colt = 0; colt < 4; colt++) {
            f32x4 acc = {0.f, 0.f, 0.f, 0.f};
            acc = __builtin_amdgcn_mfma_f32_16x16x32_bf16(a0, wb[colt * 2 + 0], acc, 0, 0, 0);
            acc = __builtin_amdgcn_mfma_f32_16x16x32_bf16(a1, wb[colt * 2 + 1], acc, 0, 0, 0);
            #pragma unroll
            for (int r = 0; r < 4; r++) {
                int nrow = tb + quad * 4 + r;
                if (nrow < cnt) {
                    float s = acc[r] + bcol[colt];
                    __hip_bfloat16 hb = __float2bfloat16(s);
                    h1buf[(size_t)nrow * 64 + colt * 16 + l15] = hb;
                    float st = __bfloat162float(hb);
                    sS[colt] += st;
                    sQ[colt] += st * st;
                }
            }
        }
    }
    // reduce across quads (cols replicated in lanes l15, +16, +32, +48)
    #pragma unroll
    for (int colt = 0; colt < 4; colt++) {
        sS[colt] += __shfl_xor(sS[colt], 16); sS[colt] += __shfl_xor(sS[colt], 32);
        sQ[colt] += __shfl_xor(sQ[colt], 16); sQ[colt] += __shfl_xor(sQ[colt], 32);
    }
    if (quad == 0) {
        int slot = (blockIdx.x & (NSHADOW - 1)) * 128;
        #pragma unroll
        for (int colt = 0; colt < 4; colt++) {
            atomicAdd(&bnacc[slot + colt * 16 + l15], sS[colt]);
            atomicAdd(&bnacc[slot + 64 + colt * 16 + l15], sQ[colt]);
        }
    }
}

// ---------------- MFMA C: xw[node] = relu(bn(h1)) @ W2 + b2 ----------------
__global__ __launch_bounds__(256) void k_cmfma(
    __hip_bfloat16* __restrict__ xw, const int* __restrict__ clist_c,
    const int* __restrict__ ccount_c, const float* __restrict__ g1c,
    const float* __restrict__ be1c, const short* __restrict__ wf2,
    const float* __restrict__ b2c, const __hip_bfloat16* __restrict__ h1buf,
    const float* __restrict__ bnacc) {
    __shared__ float lds_scale[64];
    __shared__ float lds_shift[64];
    int cnt = *ccount_c;
    int tiles = (cnt + 15) >> 4;
    int lane = threadIdx.x & 63;
    int wave = threadIdx.x >> 6;
    int wid = blockIdx.x * 4 + wave;
    int nwaves = gridDim.x * 4;
    int quad = lane >> 4;
    int l15 = lane & 15;

    if (threadIdx.x < 64) {
        float s = 0.f, q = 0.f;
        #pragma unroll
        for (int sh = 0; sh < NSHADOW; sh++) {
            s += bnacc[sh * 128 + threadIdx.x];
            q += bnacc[sh * 128 + 64 + threadIdx.x];
        }
        float fc = fmaxf((float)cnt, 1.f);
        float mean = s / fc;
        float var = q / fc - mean * mean;
        float sc = g1c[threadIdx.x] * rsqrtf(var + BN_EPS);
        lds_scale[threadIdx.x] = sc;
        lds_shift[threadIdx.x] = be1c[threadIdx.x] - mean * sc;
    }
    __syncthreads();

    bf16x8 wb[8];
    #pragma unroll
    for (int f = 0; f < 8; f++)
        wb[f] = *(const bf16x8*)(wf2 + f * 512 + lane * 8);
    float bcol[4];
    #pragma unroll
    for (int colt = 0; colt < 4; colt++) bcol[colt] = b2c[colt * 16 + l15];
    // per-lane scale/shift for its 16 channels (quad*8+j and +32)
    float scl0[8], sft0[8], scl1[8], sft1[8];
    #pragma unroll
    for (int j = 0; j < 8; j++) {
        int ch = quad * 8 + j;
        scl0[j] = lds_scale[ch];      sft0[j] = lds_shift[ch];
        scl1[j] = lds_scale[ch + 32]; sft1[j] = lds_shift[ch + 32];
    }

    for (int tile = wid; tile < tiles; tile += nwaves) {
        int tb = tile << 4;
        int row = tb + l15;
        const __hip_bfloat16* hr = h1buf + (size_t)row * 64 + quad * 8;
        bf16x8 h0 = *(const bf16x8*)hr;
        bf16x8 h1f = *(const bf16x8*)(hr + 32);
        bf16x8 a0, a1;
        #pragma unroll
        for (int j = 0; j < 8; j++) {
            a0[j] = f2bf(fmaxf(bf2f(h0[j]) * scl0[j] + sft0[j], 0.f));
            a1[j] = f2bf(fmaxf(bf2f(h1f[j]) * scl1[j] + sft1[j], 0.f));
        }
        #pragma unroll
        for (int colt = 0; colt < 4; colt++) {
            f32x4 acc = {0.f, 0.f, 0.f, 0.f};
            acc = __builtin_amdgcn_mfma_f32_16x16x32_bf16(a0, wb[colt * 2 + 0], acc, 0, 0, 0);
            acc = __builtin_amdgcn_mfma_f32_16x16x32_bf16(a1, wb[colt * 2 + 1], acc, 0, 0, 0);
            #pragma unroll
            for (int r = 0; r < 4; r++) {
                int nrow = tb + quad * 4 + r;
                if (nrow < cnt) {
                    int node = clist_c[nrow];
                    xw[(size_t)node * 64 + colt * 16 + l15] =
                        __float2bfloat16(acc[r] + bcol[colt]);
                }
            }
        }
    }
}

// ---------------- pooling (standalone, used for last layer) ----------------
__global__ void k_pool(const __hip_bfloat16* __restrict__ xw, const int* __restrict__ batch,
                       float* __restrict__ z, int t) {
    const int CHUNK = 64;
    int lane = threadIdx.x & 63;
    int wg = (blockIdx.x * blockDim.x + threadIdx.x) >> 6;
    int lo = wg * CHUNK;
    if (lo >= NN) return;
    int hi = min(lo + CHUNK, NN);
    float acc = 0.f;
    int curg = batch[lo];
    for (int n = lo; n < hi; n++) {
        int g = batch[n];
        if (g != curg) {
            atomicAdd(&z[curg * (HH * LL) + t * HH + lane], acc);
            acc = 0.f;
            curg = g;
        }
        acc += __bfloat162float(xw[(size_t)n * 64 + lane]);
    }
    atomicAdd(&z[curg * (HH * LL) + t * HH + lane], acc);
}

// ---------------- final MLP (split for parallelism, R7-proven) ----------------
__global__ __launch_bounds__(256) void k_final1(
    const float* __restrict__ z, const float* __restrict__ Wp1,
    const float* __restrict__ bp1, float* __restrict__ hbuf) {
    __shared__ float red[256];
    int g = blockIdx.x;
    int k = threadIdx.x & 63;
    int part = threadIdx.x >> 6;  // 4 parts x 48 j's
    float s = 0.f;
    #pragma unroll 8
    for (int j = part * 48; j < (part + 1) * 48; j++)
        s += z[g * (HH * LL) + j] * Wp1[j * 64 + k];
    red[threadIdx.x] = s;
    __syncthreads();
    if (part == 0)
        hbuf[g * 64 + k] = red[k] + red[64 + k] + red[128 + k] + red[192 + k] + bp1[k];
}

__global__ __launch_bounds__(256) void k_final2(
    const float* __restrict__ hbuf, const float* __restrict__ gp,
    const float* __restrict__ bep, const float* __restrict__ Wp2,
    const float* __restrict__ bp2, float* __restrict__ out) {
    __shared__ float lds[64 * 64];
    __shared__ float sscale[64];
    __shared__ float sshift[64];
    int tid = threadIdx.x;
    for (int i = tid; i < 64 * 64; i += 256) lds[i] = hbuf[i];
    __syncthreads();
    if (tid < 64) {
        float s = 0.f, q = 0.f;
        for (int g = 0; g < 64; g++) { float v = lds[g * 64 + tid]; s += v; q += v * v; }
        float mean = s / 64.f;
        float var = q / 64.f - mean * mean;
        float sc = gp[tid] * rsqrtf(var + BN_EPS);
        sscale[tid] = sc;
        sshift[tid] = bep[tid] - mean * sc;
    }
    __syncthreads();
    for (int i = tid; i < 64 * 64; i += 256) {
        int k = i & 63;
        lds[i] = fmaxf(lds[i] * sscale[k] + sshift[k], 0.f);
    }
    __syncthreads();
    for (int i = tid; i < 64 * 64; i += 256) {
        int g = i >> 6, o = i & 63;
        float s = bp2[o];
        #pragma unroll 8
        for (int k = 0; k < 64; k++) s += lds[g * 64 + k] * Wp2[k * 64 + o];
        out[g * 64 + o] = s;
    }
}

// ---------------- launch ----------------
extern "C" void kernel_launch(void* const* d_in, const int* in_sizes, int n_in,
                              void* d_out, int out_size, void* d_ws, size_t ws_size,
                              hipStream_t stream) {
    const float* x_in = (const float*)d_in[0];
    const int* labels = (const int*)d_in[1];
    const int* esrc = (const int*)d_in[2];
    const int* edst = esrc + EE;
    const int* batch = (const int*)d_in[3];
    const float* W1 = (const float*)d_in[4];
    const float* b1 = (const float*)d_in[5];
    const float* g1 = (const float*)d_in[6];
    const float* be1 = (const float*)d_in[7];
    const float* W2 = (const float*)d_in[8];
    const float* b2 = (const float*)d_in[9];
    const float* Wp1 = (const float*)d_in[10];
    const float* bp1 = (const float*)d_in[11];
    const float* gp = (const float*)d_in[12];
    const float* bep = (const float*)d_in[13];
    const float* Wp2 = (const float*)d_in[14];
    const float* bp2 = (const float*)d_in[15];
    float* out = (float*)d_out;

    char* p = (char*)d_ws;
    auto carve = [&](size_t bytes) -> void* {
        void* r = (void*)p;
        p += (bytes + 255) & ~(size_t)255;
        return r;
    };
    // ---- zeroed region (one memset) ----
    float* bnacc = (float*)carve((size_t)LL * CC * NSHADOW * 128 * 4);
    float* z     = (float*)carve((size_t)GG * HH * LL * 4);
    int*   deg   = (int*)carve((size_t)NN * 4);
    size_t zero_bytes = (size_t)(p - (char*)d_ws);
    // ---- rest ----
    int*   ccount  = (int*)carve(CC * 4);
    int*   blockcnt= (int*)carve((size_t)CC * SBLK * 4);
    int*   coffs   = (int*)carve((size_t)CC * SBLK * 4);
    int*   dpart   = (int*)carve((size_t)SBLK * 4);
    int*   dbase   = (int*)carve((size_t)SBLK * 4);
    __hip_bfloat16* xw     = (__hip_bfloat16*)carve((size_t)NN * 64 * 2);
    __hip_bfloat16* aggbuf = (__hip_bfloat16*)carve((size_t)NN * 64 * 2);
    __hip_bfloat16* h1buf  = (__hip_bfloat16*)carve((size_t)NN * 64 * 2);
    short* wf      = (short*)carve((size_t)24 * 4096 * 2);
    float* hbuf    = (float*)carve((size_t)GG * 64 * 4);
    int*   rowptr  = (int*)carve((size_t)(NN + 1) * 4);
    int*   cursor  = (int*)carve((size_t)NN * 4);
    int*   adj     = (int*)carve((size_t)EE * 4);
    int*   clist   = (int*)carve((size_t)CC * NN * 4);

    hipMemsetAsync(d_ws, 0, zero_bytes, stream);

    k_deghist<<<(EE + 255) / 256, 256, 0, stream>>>(edst, deg, labels, blockcnt, x_in, xw);
    k_wpack<<<(24 * 4096 + 255) / 256, 256, 0, stream>>>(W1, W2, wf);
    k_scancombo<<<SBLK + 1, 256, 0, stream>>>(deg, rowptr, dpart, blockcnt, coffs, ccount);
    k_dscan2<<<1, 256, 0, stream>>>(dpart, dbase, rowptr);
    k_cfill_dscan3<<<SBLK, 256, 0, stream>>>(rowptr, dbase, cursor, labels, coffs, clist);
    k_fill<<<(EE + 255) / 256, 256, 0, stream>>>(esrc, edst, cursor, adj);

    for (int t = 0; t < LL; t++) {
        for (int c = 0; c < CC; c++) {
            int tc = t * CC + c;
            int tpool = (c == 0) ? (t - 1) : -1;  // fuse previous layer's pool into gather
            k_gather<<<GIN_BLOCKS, 256, 0, stream>>>(
                xw, adj, rowptr, clist + c * NN, ccount + c, aggbuf, batch, z, tpool);
            k_lin1<<<MM_BLOCKS, 256, 0, stream>>>(
                aggbuf, ccount + c, wf + (size_t)tc * 4096, b1 + (size_t)tc * 64,
                h1buf, bnacc + (size_t)tc * NSHADOW * 128);
            k_cmfma<<<MM_BLOCKS, 256, 0, stream>>>(
                xw, clist + c * NN, ccount + c,
                g1 + (size_t)tc * 64, be1 + (size_t)tc * 64,
                wf + (size_t)(12 + tc) * 4096, b2 + (size_t)tc * 64,
                h1buf, bnacc + (size_t)tc * NSHADOW * 128);
        }
    }
    // last layer's pool (standalone)
    {
        int pool_waves = (NN + 63) / 64;
        int pool_blocks = (pool_waves * 64 + 255) / 256;
        k_pool<<<pool_blocks, 256, 0, stream>>>(xw, batch, z, LL - 1);
    }
    k_final1<<<GG, 256, 0, stream>>>(z, Wp1, bp1, hbuf);
    k_final2<<<1, 256, 0, stream>>>(hbuf, gp, bep, Wp2, bp2, out);
}

// Round 14
// 555.651 us; speedup vs baseline: 1.1770x; 1.0140x over previous
//
#include <hip/hip_runtime.h>
#include <hip/hip_bf16.h>

#define NN 50000
#define EE 800000
#define GG 64
#define LL 3
#define CC 4
#define HH 64
#define BN_EPS 1e-5f
#define NSHADOW 4
#define SBLK 196          // ceil(NN/256) node-parallel blocks
#define GIN_BLOCKS 2048   // grid-stride gather kernels (8192 waves)
#define MM_BLOCKS 256     // MFMA GEMM kernels (1024 waves >= 782 tiles)
#define ECHUNKS 3125      // ceil(EE/256)
#define NODE_RANGE 6250   // NN/8, dst-range binning for k_fill

// NOTE: harness passes ALL integer inputs as int32 (edge_index/batch included).
// NOTE: cooperative launch + grid.sync 4x SLOWER than kernel barriers (R5).
// NOTE: single-block k_final 90us latency-bound -> final MLP split (R7).
// NOTE: multi-node-per-wave gather serializes latency chains (R7/R12) — gather
//       stays 1 node/wave + big grid; R14 widens to 16 chains per node instead.
// NOTE: R11: GIN kernels are VALU-ISSUE bound; readlane broadcasts 745->646us.
// NOTE: R13: MLPs on MFMA 16x16x32 bf16: 654->563us.
//       Fragment layouts: A[m=lane&15][k=quad*8+j]; C/D[col=lane&15][row=quad*4+reg].
// NOTE: R14: k_fill binned RANGE-MAJOR (R12's blockIdx&7 interleaved ranges ->
//       no write-window locality; range-major keeps dirty adj window ~400KB in L2).

typedef __attribute__((ext_vector_type(8))) short bf16x8;
typedef __attribute__((ext_vector_type(4))) float f32x4;

__device__ __forceinline__ float bf2f(short s) {
    return __int_as_float(((int)(unsigned short)s) << 16);
}
__device__ __forceinline__ short f2bf(float v) {
    __hip_bfloat16 hb = __float2bfloat16(v);
    return *(short*)&hb;
}

// ---------------- setup kernels ----------------

// fused: x fp32->bf16 convert + degree count + cluster histogram + W-fragment pack.
// wf[m][f = colt*2+fragk][lane][j] = W_m[fragk*32 + (lane>>4)*8 + j][colt*16 + (lane&15)]
__global__ void k_deghist(const int* __restrict__ dst, int* __restrict__ deg,
                          const int* __restrict__ labels, int* __restrict__ blockcnt,
                          const float* __restrict__ x_in, __hip_bfloat16* __restrict__ xw,
                          const float* __restrict__ W1, const float* __restrict__ W2,
                          short* __restrict__ wf) {
    __shared__ int cnt[CC];
    int tid = threadIdx.x;
    for (int i = blockIdx.x * 256 + tid; i < NN * 64; i += gridDim.x * 256)
        xw[i] = __float2bfloat16(x_in[i]);
    // W pack: first 384 blocks, one element per thread (24*4096 = 98304)
    int o = blockIdx.x * 256 + tid;
    if (o < 24 * 4096) {
        int m = o >> 12;
        int r = o & 4095;
        int colt = r >> 10;
        int fragk = (r >> 9) & 1;
        int lane = (r >> 3) & 63;
        int j = r & 7;
        int k = fragk * 32 + ((lane >> 4) << 3) + j;
        int n = colt * 16 + (lane & 15);
        const float* src = (m < 12) ? (W1 + (size_t)m * 4096) : (W2 + (size_t)(m - 12) * 4096);
        wf[o] = f2bf(src[k * 64 + n]);
    }
    bool hist = (blockIdx.x < SBLK);
    if (hist && tid < CC) cnt[tid] = 0;
    __syncthreads();
    int gid = blockIdx.x * 256 + tid;
    if (gid < EE) atomicAdd(&deg[dst[gid]], 1);
    if (hist && gid < NN) atomicAdd(&cnt[labels[gid]], 1);
    __syncthreads();
    if (hist && tid < CC) blockcnt[tid * SBLK + blockIdx.x] = cnt[tid];
}

__global__ __launch_bounds__(256) void k_scancombo(
    const int* __restrict__ deg, int* __restrict__ rowptr, int* __restrict__ dpart,
    const int* __restrict__ blockcnt, int* __restrict__ coffs, int* __restrict__ ccount) {
    __shared__ int smem[CC * 256];
    int tid = threadIdx.x;
    if (blockIdx.x < SBLK) {
        int i = blockIdx.x * 256 + tid;
        int v = (i < NN) ? deg[i] : 0;
        smem[tid] = v;
        __syncthreads();
        for (int off = 1; off < 256; off <<= 1) {
            int u = (tid >= off) ? smem[tid - off] : 0;
            __syncthreads();
            smem[tid] += u;
            __syncthreads();
        }
        if (i < NN) rowptr[i] = smem[tid] - v;  // local exclusive
        if (tid == 255) dpart[blockIdx.x] = smem[255];
    } else {
        int own[CC];
        for (int c = 0; c < CC; c++) {
            own[c] = (tid < SBLK) ? blockcnt[c * SBLK + tid] : 0;
            smem[c * 256 + tid] = own[c];
        }
        __syncthreads();
        for (int off = 1; off < 256; off <<= 1) {
            int v[CC];
            for (int c = 0; c < CC; c++) v[c] = (tid >= off) ? smem[c * 256 + tid - off] : 0;
            __syncthreads();
            for (int c = 0; c < CC; c++) smem[c * 256 + tid] += v[c];
            __syncthreads();
        }
        if (tid < SBLK)
            for (int c = 0; c < CC; c++) coffs[c * SBLK + tid] = smem[c * 256 + tid] - own[c];
        if (tid == 0)
            for (int c = 0; c < CC; c++) ccount[c] = smem[c * 256 + 255];
    }
}

__global__ __launch_bounds__(256) void k_dscan2(int* __restrict__ dpart,
                                                int* __restrict__ dbase,
                                                int* __restrict__ rowptr) {
    __shared__ int s[256];
    int tid = threadIdx.x;
    int v = (tid < SBLK) ? dpart[tid] : 0;
    s[tid] = v;
    __syncthreads();
    for (int off = 1; off < 256; off <<= 1) {
        int u = (tid >= off) ? s[tid - off] : 0;
        __syncthreads();
        s[tid] += u;
        __syncthreads();
    }
    if (tid < SBLK) dbase[tid] = s[tid] - v;
    if (tid == 0) rowptr[NN] = EE;
}

__global__ __launch_bounds__(256) void k_cfill_dscan3(
    int* __restrict__ rowptr, const int* __restrict__ dbase, int* __restrict__ cursor,
    const int* __restrict__ labels, const int* __restrict__ coffs, int* __restrict__ clist) {
    __shared__ int pos[CC];
    int tid = threadIdx.x;
    if (tid < CC) pos[tid] = coffs[tid * SBLK + blockIdx.x];
    __syncthreads();
    int i = blockIdx.x * 256 + tid;
    if (i < NN) {
        int r = rowptr[i] + dbase[blockIdx.x];
        rowptr[i] = r;
        cursor[i] = r;
        int c = labels[i];
        int p = atomicAdd(&pos[c], 1);
        clist[c * NN + p] = i;
    }
}

// RANGE-MAJOR binned CSR fill: blocks [r*ECHUNKS,(r+1)*ECHUNKS) handle dst range r.
// Blocks dispatch roughly in order -> dirty adj window ~400KB stays L2-resident.
// adj stores BYTE offsets of bf16 rows: src*128 = src<<7
__global__ void k_fill(const int* __restrict__ src, const int* __restrict__ dst,
                       int* __restrict__ cursor, int* __restrict__ adj) {
    int range = blockIdx.x / ECHUNKS;
    int e = (blockIdx.x - range * ECHUNKS) * 256 + threadIdx.x;
    if (e < EE) {
        int d = dst[e];
        int lo = range * NODE_RANGE;
        if (d >= lo && d < lo + NODE_RANGE) {
            int pos = atomicAdd(&cursor[d], 1);
            adj[pos] = src[e] << 7;
        }
    }
}

// ---------------- gather kernel (1 node/wave, 16 indep chains) ----------------
// agg[idx] = x[node] + sum_{j->node} x[j]  (bf16 out).
// Optional fused pool of previous layer (tpool >= 0).
__global__ __launch_bounds__(256) void k_gather(
    const __hip_bfloat16* __restrict__ xw, const int* __restrict__ adj,
    const int* __restrict__ rowptr, const int* __restrict__ clist_c,
    const int* __restrict__ ccount_c, __hip_bfloat16* __restrict__ aggbuf,
    const int* __restrict__ batch, float* __restrict__ z, int tpool) {
    int cnt = *ccount_c;
    int lane = threadIdx.x & 63;
    int wave = threadIdx.x >> 6;
    int wid = blockIdx.x * 4 + wave;
    int nwaves = gridDim.x * 4;
    const char* xwb = (const char*)xw;
    int idx = wid;
    int node_next = (idx < cnt) ? clist_c[idx] : 0;
    for (; idx < cnt; idx += nwaves) {
        int node = node_next;
        int nidx = idx + nwaves;
        if (nidx < cnt) node_next = clist_c[nidx];  // prefetch next node id
        int rb = rowptr[node], re = rowptr[node + 1];
        float a[16];
        a[0] = __bfloat162float(xw[(size_t)node * 64 + lane]);
        #pragma unroll
        for (int u = 1; u < 16; u++) a[u] = 0.f;
        int base = rb, rem = re - rb;
        while (rem > 0) {
            int take = min(rem, 64);
            int nb = adj[base + min(lane, take - 1)];  // byte offsets
            int j = 0;
            for (; j + 16 <= take; j += 16) {
                #pragma unroll
                for (int u = 0; u < 16; u++) {
                    int o = __builtin_amdgcn_readlane(nb, j + u);
                    a[u] += __bfloat162float(((const __hip_bfloat16*)(xwb + o))[lane]);
                }
            }
            for (; j + 8 <= take; j += 8) {
                #pragma unroll
                for (int u = 0; u < 8; u++) {
                    int o = __builtin_amdgcn_readlane(nb, j + u);
                    a[u] += __bfloat162float(((const __hip_bfloat16*)(xwb + o))[lane]);
                }
            }
            for (; j < take; j++) {
                int o = __builtin_amdgcn_readlane(nb, j);
                a[0] += __bfloat162float(((const __hip_bfloat16*)(xwb + o))[lane]);
            }
            base += take; rem -= take;
        }
        float acc = (((a[0] + a[1]) + (a[2] + a[3])) + ((a[4] + a[5]) + (a[6] + a[7]))) +
                    (((a[8] + a[9]) + (a[10] + a[11])) + ((a[12] + a[13]) + (a[14] + a[15])));
        aggbuf[(size_t)idx * 64 + lane] = __float2bfloat16(acc);
    }
    // -------- fused pool of previous layer (reads same xw state) --------
    if (tpool >= 0) {
        int lo = wid * 64;
        if (lo < NN) {
            int hi = min(lo + 64, NN);
            float acc = 0.f;
            int curg = batch[lo];
            for (int n = lo; n < hi; n++) {
                int g = batch[n];
                if (g != curg) {
                    atomicAdd(&z[curg * (HH * LL) + tpool * HH + lane], acc);
                    acc = 0.f;
                    curg = g;
                }
                acc += __bfloat162float(xw[(size_t)n * 64 + lane]);
            }
            atomicAdd(&z[curg * (HH * LL) + tpool * HH + lane], acc);
        }
    }
}

// ---------------- MFMA Lin1: h1 = agg @ W1 + b1 ; BN partials ----------------
__global__ __launch_bounds__(256) void k_lin1(
    const __hip_bfloat16* __restrict__ aggbuf, const int* __restrict__ ccount_c,
    const short* __restrict__ wf1, const float* __restrict__ b1c,
    __hip_bfloat16* __restrict__ h1buf, float* __restrict__ bnacc) {
    int cnt = *ccount_c;
    int tiles = (cnt + 15) >> 4;
    int lane = threadIdx.x & 63;
    int wave = threadIdx.x >> 6;
    int wid = blockIdx.x * 4 + wave;
    int nwaves = gridDim.x * 4;
    int quad = lane >> 4;
    int l15 = lane & 15;

    bf16x8 wb[8];
    #pragma unroll
    for (int f = 0; f < 8; f++)
        wb[f] = *(const bf16x8*)(wf1 + f * 512 + lane * 8);
    float bcol[4];
    #pragma unroll
    for (int colt = 0; colt < 4; colt++) bcol[colt] = b1c[colt * 16 + l15];

    float sS[4] = {0.f, 0.f, 0.f, 0.f};
    float sQ[4] = {0.f, 0.f, 0.f, 0.f};

    for (int tile = wid; tile < tiles; tile += nwaves) {
        int tb = tile << 4;
        int row = tb + l15;
        const __hip_bfloat16* ar = aggbuf + (size_t)row * 64 + quad * 8;
        bf16x8 a0 = *(const bf16x8*)ar;
        bf16x8 a1 = *(const bf16x8*)(ar + 32);
        #pragma unroll
        for (int colt = 0; colt < 4; colt++) {
            f32x4 acc = {0.f, 0.f, 0.f, 0.f};
            acc = __builtin_amdgcn_mfma_f32_16x16x32_bf16(a0, wb[colt * 2 + 0], acc, 0, 0, 0);
            acc = __builtin_amdgcn_mfma_f32_16x16x32_bf16(a1, wb[colt * 2 + 1], acc, 0, 0, 0);
            #pragma unroll
            for (int r = 0; r < 4; r++) {
                int nrow = tb + quad * 4 + r;
                if (nrow < cnt) {
                    float s = acc[r] + bcol[colt];
                    __hip_bfloat16 hb = __float2bfloat16(s);
                    h1buf[(size_t)nrow * 64 + colt * 16 + l15] = hb;
                    float st = __bfloat162float(hb);
                    sS[colt] += st;
                    sQ[colt] += st * st;
                }
            }
        }
    }
    // reduce across quads (cols replicated in lanes l15, +16, +32, +48)
    #pragma unroll
    for (int colt = 0; colt < 4; colt++) {
        sS[colt] += __shfl_xor(sS[colt], 16); sS[colt] += __shfl_xor(sS[colt], 32);
        sQ[colt] += __shfl_xor(sQ[colt], 16); sQ[colt] += __shfl_xor(sQ[colt], 32);
    }
    if (quad == 0) {
        int slot = (blockIdx.x & (NSHADOW - 1)) * 128;
        #pragma unroll
        for (int colt = 0; colt < 4; colt++) {
            atomicAdd(&bnacc[slot + colt * 16 + l15], sS[colt]);
            atomicAdd(&bnacc[slot + 64 + colt * 16 + l15], sQ[colt]);
        }
    }
}

// ---------------- MFMA C: xw[node] = relu(bn(h1)) @ W2 + b2 ----------------
__global__ __launch_bounds__(256) void k_cmfma(
    __hip_bfloat16* __restrict__ xw, const int* __restrict__ clist_c,
    const int* __restrict__ ccount_c, const float* __restrict__ g1c,
    const float* __restrict__ be1c, const short* __restrict__ wf2,
    const float* __restrict__ b2c, const __hip_bfloat16* __restrict__ h1buf,
    const float* __restrict__ bnacc) {
    __shared__ float lds_scale[64];
    __shared__ float lds_shift[64];
    int cnt = *ccount_c;
    int tiles = (cnt + 15) >> 4;
    int lane = threadIdx.x & 63;
    int wave = threadIdx.x >> 6;
    int wid = blockIdx.x * 4 + wave;
    int nwaves = gridDim.x * 4;
    int quad = lane >> 4;
    int l15 = lane & 15;

    if (threadIdx.x < 64) {
        float s = 0.f, q = 0.f;
        #pragma unroll
        for (int sh = 0; sh < NSHADOW; sh++) {
            s += bnacc[sh * 128 + threadIdx.x];
            q += bnacc[sh * 128 + 64 + threadIdx.x];
        }
        float fc = fmaxf((float)cnt, 1.f);
        float mean = s / fc;
        float var = q / fc - mean * mean;
        float sc = g1c[threadIdx.x] * rsqrtf(var + BN_EPS);
        lds_scale[threadIdx.x] = sc;
        lds_shift[threadIdx.x] = be1c[threadIdx.x] - mean * sc;
    }
    __syncthreads();

    bf16x8 wb[8];
    #pragma unroll
    for (int f = 0; f < 8; f++)
        wb[f] = *(const bf16x8*)(wf2 + f * 512 + lane * 8);
    float bcol[4];
    #pragma unroll
    for (int colt = 0; colt < 4; colt++) bcol[colt] = b2c[colt * 16 + l15];
    // per-lane scale/shift for its 16 channels (quad*8+j and +32)
    float scl0[8], sft0[8], scl1[8], sft1[8];
    #pragma unroll
    for (int j = 0; j < 8; j++) {
        int ch = quad * 8 + j;
        scl0[j] = lds_scale[ch];      sft0[j] = lds_shift[ch];
        scl1[j] = lds_scale[ch + 32]; sft1[j] = lds_shift[ch + 32];
    }

    for (int tile = wid; tile < tiles; tile += nwaves) {
        int tb = tile << 4;
        int row = tb + l15;
        const __hip_bfloat16* hr = h1buf + (size_t)row * 64 + quad * 8;
        bf16x8 h0 = *(const bf16x8*)hr;
        bf16x8 h1f = *(const bf16x8*)(hr + 32);
        bf16x8 a0, a1;
        #pragma unroll
        for (int j = 0; j < 8; j++) {
            a0[j] = f2bf(fmaxf(bf2f(h0[j]) * scl0[j] + sft0[j], 0.f));
            a1[j] = f2bf(fmaxf(bf2f(h1f[j]) * scl1[j] + sft1[j], 0.f));
        }
        #pragma unroll
        for (int colt = 0; colt < 4; colt++) {
            f32x4 acc = {0.f, 0.f, 0.f, 0.f};
            acc = __builtin_amdgcn_mfma_f32_16x16x32_bf16(a0, wb[colt * 2 + 0], acc, 0, 0, 0);
            acc = __builtin_amdgcn_mfma_f32_16x16x32_bf16(a1, wb[colt * 2 + 1], acc, 0, 0, 0);
            #pragma unroll
            for (int r = 0; r < 4; r++) {
                int nrow = tb + quad * 4 + r;
                if (nrow < cnt) {
                    int node = clist_c[nrow];
                    xw[(size_t)node * 64 + colt * 16 + l15] =
                        __float2bfloat16(acc[r] + bcol[colt]);
                }
            }
        }
    }
}

// ---------------- pooling (standalone, used for last layer) ----------------
__global__ void k_pool(const __hip_bfloat16* __restrict__ xw, const int* __restrict__ batch,
                       float* __restrict__ z, int t) {
    const int CHUNK = 64;
    int lane = threadIdx.x & 63;
    int wg = (blockIdx.x * blockDim.x + threadIdx.x) >> 6;
    int lo = wg * CHUNK;
    if (lo >= NN) return;
    int hi = min(lo + CHUNK, NN);
    float acc = 0.f;
    int curg = batch[lo];
    for (int n = lo; n < hi; n++) {
        int g = batch[n];
        if (g != curg) {
            atomicAdd(&z[curg * (HH * LL) + t * HH + lane], acc);
            acc = 0.f;
            curg = g;
        }
        acc += __bfloat162float(xw[(size_t)n * 64 + lane]);
    }
    atomicAdd(&z[curg * (HH * LL) + t * HH + lane], acc);
}

// ---------------- final MLP (split for parallelism, R7-proven) ----------------
__global__ __launch_bounds__(256) void k_final1(
    const float* __restrict__ z, const float* __restrict__ Wp1,
    const float* __restrict__ bp1, float* __restrict__ hbuf) {
    __shared__ float red[256];
    int g = blockIdx.x;
    int k = threadIdx.x & 63;
    int part = threadIdx.x >> 6;  // 4 parts x 48 j's
    float s = 0.f;
    #pragma unroll 8
    for (int j = part * 48; j < (part + 1) * 48; j++)
        s += z[g * (HH * LL) + j] * Wp1[j * 64 + k];
    red[threadIdx.x] = s;
    __syncthreads();
    if (part == 0)
        hbuf[g * 64 + k] = red[k] + red[64 + k] + red[128 + k] + red[192 + k] + bp1[k];
}

__global__ __launch_bounds__(256) void k_final2(
    const float* __restrict__ hbuf, const float* __restrict__ gp,
    const float* __restrict__ bep, const float* __restrict__ Wp2,
    const float* __restrict__ bp2, float* __restrict__ out) {
    __shared__ float lds[64 * 64];
    __shared__ float sscale[64];
    __shared__ float sshift[64];
    int tid = threadIdx.x;
    for (int i = tid; i < 64 * 64; i += 256) lds[i] = hbuf[i];
    __syncthreads();
    if (tid < 64) {
        float s = 0.f, q = 0.f;
        for (int g = 0; g < 64; g++) { float v = lds[g * 64 + tid]; s += v; q += v * v; }
        float mean = s / 64.f;
        float var = q / 64.f - mean * mean;
        float sc = gp[tid] * rsqrtf(var + BN_EPS);
        sscale[tid] = sc;
        sshift[tid] = bep[tid] - mean * sc;
    }
    __syncthreads();
    for (int i = tid; i < 64 * 64; i += 256) {
        int k = i & 63;
        lds[i] = fmaxf(lds[i] * sscale[k] + sshift[k], 0.f);
    }
    __syncthreads();
    for (int i = tid; i < 64 * 64; i += 256) {
        int g = i >> 6, o = i & 63;
        float s = bp2[o];
        #pragma unroll 8
        for (int k = 0; k < 64; k++) s += lds[g * 64 + k] * Wp2[k * 64 + o];
        out[g * 64 + o] = s;
    }
}

// ---------------- launch ----------------
extern "C" void kernel_launch(void* const* d_in, const int* in_sizes, int n_in,
                              void* d_out, int out_size, void* d_ws, size_t ws_size,
                              hipStream_t stream) {
    const float* x_in = (const float*)d_in[0];
    const int* labels = (const int*)d_in[1];
    const int* esrc = (const int*)d_in[2];
    const int* edst = esrc + EE;
    const int* batch = (const int*)d_in[3];
    const float* W1 = (const float*)d_in[4];
    const float* b1 = (const float*)d_in[5];
    const float* g1 = (const float*)d_in[6];
    const float* be1 = (const float*)d_in[7];
    const float* W2 = (const float*)d_in[8];
    const float* b2 = (const float*)d_in[9];
    const float* Wp1 = (const float*)d_in[10];
    const float* bp1 = (const float*)d_in[11];
    const float* gp = (const float*)d_in[12];
    const float* bep = (const float*)d_in[13];
    const float* Wp2 = (const float*)d_in[14];
    const float* bp2 = (const float*)d_in[15];
    float* out = (float*)d_out;

    char* p = (char*)d_ws;
    auto carve = [&](size_t bytes) -> void* {
        void* r = (void*)p;
        p += (bytes + 255) & ~(size_t)255;
        return r;
    };
    // ---- zeroed region (one memset) ----
    float* bnacc = (float*)carve((size_t)LL * CC * NSHADOW * 128 * 4);
    float* z     = (float*)carve((size_t)GG * HH * LL * 4);
    int*   deg   = (int*)carve((size_t)NN * 4);
    size_t zero_bytes = (size_t)(p - (char*)d_ws);
    // ---- rest ----
    int*   ccount  = (int*)carve(CC * 4);
    int*   blockcnt= (int*)carve((size_t)CC * SBLK * 4);
    int*   coffs   = (int*)carve((size_t)CC * SBLK * 4);
    int*   dpart   = (int*)carve((size_t)SBLK * 4);
    int*   dbase   = (int*)carve((size_t)SBLK * 4);
    __hip_bfloat16* xw     = (__hip_bfloat16*)carve((size_t)NN * 64 * 2);
    __hip_bfloat16* aggbuf = (__hip_bfloat16*)carve((size_t)NN * 64 * 2);
    __hip_bfloat16* h1buf  = (__hip_bfloat16*)carve((size_t)NN * 64 * 2);
    short* wf      = (short*)carve((size_t)24 * 4096 * 2);
    float* hbuf    = (float*)carve((size_t)GG * 64 * 4);
    int*   rowptr  = (int*)carve((size_t)(NN + 1) * 4);
    int*   cursor  = (int*)carve((size_t)NN * 4);
    int*   adj     = (int*)carve((size_t)EE * 4);
    int*   clist   = (int*)carve((size_t)CC * NN * 4);

    hipMemsetAsync(d_ws, 0, zero_bytes, stream);

    k_deghist<<<ECHUNKS, 256, 0, stream>>>(edst, deg, labels, blockcnt, x_in, xw, W1, W2, wf);
    k_scancombo<<<SBLK + 1, 256, 0, stream>>>(deg, rowptr, dpart, blockcnt, coffs, ccount);
    k_dscan2<<<1, 256, 0, stream>>>(dpart, dbase, rowptr);
    k_cfill_dscan3<<<SBLK, 256, 0, stream>>>(rowptr, dbase, cursor, labels, coffs, clist);
    k_fill<<<ECHUNKS * 8, 256, 0, stream>>>(esrc, edst, cursor, adj);

    for (int t = 0; t < LL; t++) {
        for (int c = 0; c < CC; c++) {
            int tc = t * CC + c;
            int tpool = (c == 0) ? (t - 1) : -1;  // fuse previous layer's pool into gather
            k_gather<<<GIN_BLOCKS, 256, 0, stream>>>(
                xw, adj, rowptr, clist + c * NN, ccount + c, aggbuf, batch, z, tpool);
            k_lin1<<<MM_BLOCKS, 256, 0, stream>>>(
                aggbuf, ccount + c, wf + (size_t)tc * 4096, b1 + (size_t)tc * 64,
                h1buf, bnacc + (size_t)tc * NSHADOW * 128);
            k_cmfma<<<MM_BLOCKS, 256, 0, stream>>>(
                xw, clist + c * NN, ccount + c,
                g1 + (size_t)tc * 64, be1 + (size_t)tc * 64,
                wf + (size_t)(12 + tc) * 4096, b2 + (size_t)tc * 64,
                h1buf, bnacc + (size_t)tc * NSHADOW * 128);
        }
    }
    // last layer's pool (standalone)
    {
        int pool_waves = (NN + 63) / 64;
        int pool_blocks = (pool_waves * 64 + 255) / 256;
        k_pool<<<pool_blocks, 256, 0, stream>>>(xw, batch, z, LL - 1);
    }
    k_final1<<<GG, 256, 0, stream>>>(z, Wp1, bp1, hbuf);
    k_final2<<<1, 256, 0, stream>>>(hbuf, gp, bep, Wp2, bp2, out);
}